// Round 14
// baseline (495.474 us; speedup 1.0000x reference)
//
#include <hip/hip_runtime.h>
#include <math.h>

#define DD 128
#define CHUNK 8192
#define CAP 5120

typedef __attribute__((ext_vector_type(8))) short bf16x8;  // 8 bf16 (4 VGPR)
typedef __attribute__((ext_vector_type(4))) float f32x4;   // 4 fp32 acc
typedef __attribute__((ext_vector_type(4))) unsigned short u16x4;

__device__ __forceinline__ ushort f2bf(float f) {
    union { float f; unsigned u; } v; v.f = f;
    unsigned r = v.u + 0x7fff + ((v.u >> 16) & 1);   // RNE
    return (ushort)(r >> 16);
}

__device__ __forceinline__ float2 bfp(unsigned u) {
    union { unsigned x; float f; } a, b;
    a.x = u << 16;
    b.x = u & 0xffff0000u;
    return make_float2(a.f, b.f);
}

// ==================== weight prep (once per launch) ====================
__global__ __launch_bounds__(256) void combine_all(const float* __restrict__ qkv_w,
                                                   const float* __restrict__ qkv_b,
                                                   const float* __restrict__ edge_W,
                                                   float* __restrict__ WC,
                                                   float* __restrict__ BCq)
{
    const int z = blockIdx.y;          // (L<<1)|t
    const int L = z >> 1, t = z & 1;
    const float* wq = qkv_w + (((size_t)L * 2 + t) * 3 + 0) * DD * DD;
    const float* bq = qkv_b + (((size_t)L * 2 + t) * 3 + 0) * DD;
    const float* We = edge_W + ((size_t)L * 2 + t) * DD * DD;
    float* Wz = WC + (size_t)z * DD * DD;
    float* Bz = BCq + (size_t)z * DD;

    const int tid = threadIdx.x;
    const int i = blockIdx.x * 2 + (tid >> 7);
    const int j = tid & 127;
    float sum = 0.f;
    for (int k = 0; k < DD; ++k) sum = fmaf(wq[i * DD + k], We[k * DD + j], sum);
    Wz[i * DD + j] = sum;
    if (blockIdx.x == 0 && tid < DD) {
        float s2 = 0.f;
        for (int k = 0; k < DD; ++k) s2 = fmaf(bq[k], We[k * DD + j], s2);
        Bz[j] = s2;
    }
}

// Pack per z=(L,t): planes [q(Wc z) | v(wv L,t) | k(wk L,t)]
__global__ __launch_bounds__(256) void pack_all(const float* __restrict__ qkv_w,
                                                const float* __restrict__ qkv_b,
                                                const float* __restrict__ WC,
                                                const float* __restrict__ BCq,
                                                ushort* __restrict__ W3P,
                                                float* __restrict__ B3)
{
    const int z = blockIdx.y;
    const int L = z >> 1, t = z & 1;
    const int ci = blockIdx.x * 256 + threadIdx.x;     // 0..6143
    const int cb = ci >> 11;
    const int ct = (ci >> 8) & 7;
    const int ks = (ci >> 6) & 3;
    const int l  = ci & 63;
    const int c3 = cb * 128 + ct * 16 + (l & 15);
    const int k0 = ks * 32 + (l >> 4) * 8;

    const float* wv = qkv_w + (((size_t)L * 2 + t) * 3 + 2) * DD * DD;
    const float* wk = qkv_w + (((size_t)L * 2 + t) * 3 + 1) * DD * DD;
    const float* src;
    int cc;
    if (c3 < 128)      { src = WC + (size_t)z * DD * DD; cc = c3; }
    else if (c3 < 256) { src = wv; cc = c3 - 128; }
    else               { src = wk; cc = c3 - 256; }

    ushort h[8];
    #pragma unroll
    for (int j = 0; j < 8; ++j) h[j] = f2bf(src[(size_t)(k0 + j) * DD + cc]);
    ushort* dst = W3P + (size_t)z * 6144 * 8 + (size_t)ci * 8;
    #pragma unroll
    for (int j = 0; j < 8; ++j) dst[j] = h[j];

    if (ci < 384) {
        float bv;
        if (ci < 128)      bv = BCq[(size_t)z * DD + ci];
        else if (ci < 256) bv = qkv_b[(((size_t)L * 2 + t) * 3 + 2) * DD + (ci - 128)];
        else               bv = qkv_b[(((size_t)L * 2 + t) * 3 + 1) * DD + (ci - 256)];
        B3[(size_t)z * 384 + ci] = bv;
    }
}

// ==================== fused MFMA GEMM: swapped operands, 2 node-tiles/wave ====================
// grid (ceil(N/128), 2): block (x, t) computes q,v,k for 128 nodes of type t.
// mfma(W_frag, X_frag, acc): D row=feature ((lane>>4)*4+reg), col=node (lane&15).
template<bool F32_IN, bool RELU_IN>
__global__ __launch_bounds__(256, 4) void gemm_mfma(const void* __restrict__ Xav,
                                                    const void* __restrict__ Xbv,
                                                    const ushort* __restrict__ WpL,
                                                    const float* __restrict__ bL,
                                                    ushort* __restrict__ QVa,
                                                    ushort* __restrict__ FKa,
                                                    ushort* __restrict__ QVb,
                                                    ushort* __restrict__ FKb,
                                                    int N)
{
    const int t = blockIdx.y;
    ushort* QV = t ? QVb : QVa;
    ushort* FK = t ? FKb : FKa;
    const ushort* Wz = WpL + (size_t)t * 49152;
    const float* bz0 = bL + t * 384;

    __shared__ ushort Ws[16384];   // 32 KB, one plane at a time

    const int tid  = threadIdx.x;
    const int wave = tid >> 6;
    const int lane = tid & 63;
    const int node0 = blockIdx.x * 128 + wave * 16 + (lane & 15);        // tile 0
    const int node1 = node0 + 64;                                        // tile 1
    const int kc   = (lane >> 4) * 8;
    const int frow = (lane >> 4) * 4;
    const bool ok0 = node0 < N;
    const bool ok1 = node1 < N;

    // X fragments for both tiles, loaded ONCE.
    bf16x8 x0[4], x1[4];
#define LOAD_X(NODE, OK, DST)                                                    \
    if (F32_IN) {                                                                \
        const float* X = (const float*)(t ? Xbv : Xav);                          \
        const float* xr = X + (size_t)(NODE) * DD + kc;                          \
        _Pragma("unroll")                                                        \
        for (int ks = 0; ks < 4; ++ks) {                                         \
            bf16x8 h = (bf16x8){0,0,0,0,0,0,0,0};                                \
            if (OK) {                                                            \
                float4 v0 = *(const float4*)&xr[ks * 32];                        \
                float4 v1 = *(const float4*)&xr[ks * 32 + 4];                    \
                h[0]=(short)f2bf(v0.x); h[1]=(short)f2bf(v0.y);                  \
                h[2]=(short)f2bf(v0.z); h[3]=(short)f2bf(v0.w);                  \
                h[4]=(short)f2bf(v1.x); h[5]=(short)f2bf(v1.y);                  \
                h[6]=(short)f2bf(v1.z); h[7]=(short)f2bf(v1.w);                  \
            }                                                                    \
            DST[ks] = h;                                                         \
        }                                                                        \
    } else {                                                                     \
        const ushort* X = (const ushort*)(t ? Xbv : Xav);                        \
        const ushort* xr = X + (size_t)(NODE) * DD + kc;                         \
        _Pragma("unroll")                                                        \
        for (int ks = 0; ks < 4; ++ks) {                                         \
            bf16x8 h = (bf16x8){0,0,0,0,0,0,0,0};                                \
            if (OK) h = *(const bf16x8*)&xr[ks * 32];                            \
            if (RELU_IN) {                                                       \
                _Pragma("unroll")                                                \
                for (int j = 0; j < 8; ++j)                                      \
                    h[j] = (short)(((ushort)h[j] & 0x8000u) ? 0 : (ushort)h[j]); \
            }                                                                    \
            DST[ks] = h;                                                         \
        }                                                                        \
    }

    LOAD_X(node0, ok0, x0)
    LOAD_X(node1, ok1, x1)
#undef LOAD_X

    #pragma unroll
    for (int p = 0; p < 3; ++p) {
        if (p) __syncthreads();   // all waves done reading Ws for plane p-1
        #pragma unroll
        for (int i = 0; i < 8; ++i) {
            const int c = tid + i * 256;
            *(float4*)&Ws[(size_t)c * 8] = ((const float4*)(Wz + (size_t)p * 16384))[c];
        }
        __syncthreads();

        ushort* outp   = (p == 2) ? FK : QV;
        const int stride = (p == 2) ? 128 : 256;
        const int off    = (p == 1) ? 128 : 0;
        const float* bzp = bz0 + p * 128;

        #pragma unroll
        for (int tile = 0; tile < 2; ++tile) {
            const int node = tile ? node1 : node0;
            const bool ok  = tile ? ok1 : ok0;

            f32x4 acc[8];
            #pragma unroll
            for (int ct = 0; ct < 8; ++ct) {
                acc[ct] = (f32x4){0.f, 0.f, 0.f, 0.f};
                #pragma unroll
                for (int ks = 0; ks < 4; ++ks) {
                    bf16x8 w = *(const bf16x8*)&Ws[(size_t)((ct * 4 + ks) * 64 + lane) * 8];
                    acc[ct] = __builtin_amdgcn_mfma_f32_16x16x32_bf16(
                        w, tile ? x1[ks] : x0[ks], acc[ct], 0, 0, 0);
                }
            }
            if (ok) {
                ushort* orow = outp + (size_t)node * stride + off;
                #pragma unroll
                for (int ct = 0; ct < 8; ++ct) {
                    const float4 bv = *(const float4*)&bzp[ct * 16 + frow];
                    u16x4 o;
                    o[0] = f2bf(acc[ct][0] + bv.x);
                    o[1] = f2bf(acc[ct][1] + bv.y);
                    o[2] = f2bf(acc[ct][2] + bv.z);
                    o[3] = f2bf(acc[ct][3] + bv.w);
                    *(u16x4*)&orow[ct * 16 + frow] = o;   // single 8B store
                }
            }
        }
    }
}

// ==================== CSR build: two-level bucket counting sort ====================
__global__ __launch_bounds__(256) void zero_ints(int* __restrict__ p, int n)
{
    int i = blockIdx.x * 256 + threadIdx.x;
    if (i < n) p[i] = 0;
}

__global__ __launch_bounds__(256) void bkt_hist(const int* __restrict__ dst0,
                                                const int* __restrict__ dst1,
                                                int* __restrict__ bcnt, int nE)
{
    const int t = blockIdx.y;
    const int* dst = t ? dst1 : dst0;
    __shared__ int h[256];
    h[threadIdx.x] = 0;
    __syncthreads();
    for (int e = blockIdx.x * 256 + threadIdx.x; e < nE; e += gridDim.x * 256)
        atomicAdd(&h[dst[e] >> 8], 1);
    __syncthreads();
    if (h[threadIdx.x]) atomicAdd(&bcnt[t * 256 + threadIdx.x], h[threadIdx.x]);
}

__global__ __launch_bounds__(64) void bkt_scan(const int* __restrict__ bcnt,
                                               int* __restrict__ bbase,
                                               int* __restrict__ bcur,
                                               int* __restrict__ offs0,
                                               int* __restrict__ offs1, int N, int nE)
{
    if (threadIdx.x < 2) {
        int t = threadIdx.x;
        int run = 0;
        for (int i = 0; i < 256; ++i) {
            int v = bcnt[t * 256 + i];
            bbase[t * 256 + i] = run;
            bcur[t * 256 + i] = run;
            run += v;
        }
        if (t == 0) offs0[N] = nE; else offs1[N] = nE;
    }
}

__global__ __launch_bounds__(256) void bkt_part(const int* __restrict__ src0,
                                                const int* __restrict__ dst0,
                                                const int* __restrict__ src1,
                                                const int* __restrict__ dst1,
                                                int* __restrict__ bcur,
                                                unsigned* __restrict__ stage0,
                                                unsigned* __restrict__ stage1,
                                                int nE, int nbkt)
{
    const int t = blockIdx.y;
    const int* src = t ? src1 : src0;
    const int* dst = t ? dst1 : dst0;
    unsigned* stage = t ? stage1 : stage0;
    int* bc = bcur + t * 256;

    __shared__ unsigned ebuf[CHUNK];                   // 32 KB
    __shared__ int cnt[256], loff[256], cur[256], resv[256];

    const int tid  = threadIdx.x;
    const int e0   = blockIdx.x * CHUNK;
    const int ecnt = min(CHUNK, nE - e0);

    cnt[tid] = 0;
    __syncthreads();

    unsigned pk[CHUNK / 256];
    #pragma unroll
    for (int i = 0; i < CHUNK / 256; ++i) {
        const int le = i * 256 + tid;
        unsigned p = 0xFFFFFFFFu;
        if (le < ecnt) {
            int d = dst[e0 + le], s = src[e0 + le];
            p = ((unsigned)(d >> 8) << 24) | ((unsigned)(d & 255) << 16) | (unsigned)s;
            atomicAdd(&cnt[d >> 8], 1);
        }
        pk[i] = p;
    }
    __syncthreads();

    int v = cnt[tid];
    loff[tid] = v;
    __syncthreads();
    for (int off = 1; off < 256; off <<= 1) {
        int a = (tid >= off) ? loff[tid - off] : 0;
        __syncthreads();
        loff[tid] += a;
        __syncthreads();
    }
    int excl = loff[tid] - v;
    __syncthreads();
    loff[tid] = excl;
    cur[tid]  = excl;
    __syncthreads();

    #pragma unroll
    for (int i = 0; i < CHUNK / 256; ++i) {
        unsigned p = pk[i];
        if (p != 0xFFFFFFFFu) {
            int b = p >> 24;
            int pos = atomicAdd(&cur[b], 1);
            ebuf[pos] = p;
        }
    }
    __syncthreads();

    if (tid < nbkt && cnt[tid] > 0) resv[tid] = atomicAdd(&bc[tid], cnt[tid]);
    __syncthreads();

    const int wv = tid >> 6, ln = tid & 63;
    for (int b = wv; b < nbkt; b += 4) {
        const int c = cnt[b];
        if (c == 0) continue;
        const int lo = loff[b];
        const int rb = resv[b];
        for (int i = ln; i < c; i += 64) stage[rb + i] = ebuf[lo + i];
    }
}

__global__ __launch_bounds__(256) void bkt_fill(const unsigned* __restrict__ stage0,
                                                const unsigned* __restrict__ stage1,
                                                const int* __restrict__ bcnt,
                                                const int* __restrict__ bbase,
                                                int* __restrict__ offs0,
                                                int* __restrict__ offs1,
                                                int* __restrict__ col0,
                                                int* __restrict__ col1, int N)
{
    const int b = blockIdx.x, t = blockIdx.y;
    const unsigned* stage = t ? stage1 : stage0;
    int* offs = t ? offs1 : offs0;
    int* col  = t ? col1 : col0;
    const int base = bbase[t * 256 + b];
    int cb = bcnt[t * 256 + b];
    if (cb > CAP) cb = CAP;

    __shared__ unsigned ebuf[CAP];
    __shared__ int colbuf[CAP];
    __shared__ int dcnt[256], doff[256], dcur[256];

    const int tid = threadIdx.x;
    dcnt[tid] = 0;
    __syncthreads();

    for (int i = tid; i < cb; i += 256) {
        unsigned p = stage[base + i];
        ebuf[i] = p;
        atomicAdd(&dcnt[(p >> 16) & 255], 1);
    }
    __syncthreads();

    int v = dcnt[tid];
    doff[tid] = v;
    __syncthreads();
    for (int off = 1; off < 256; off <<= 1) {
        int a = (tid >= off) ? doff[tid - off] : 0;
        __syncthreads();
        doff[tid] += a;
        __syncthreads();
    }
    int excl = doff[tid] - v;
    dcur[tid] = excl;
    const int node = (b << 8) + tid;
    if (node < N) offs[node] = base + excl;
    __syncthreads();

    for (int i = tid; i < cb; i += 256) {
        unsigned p = ebuf[i];
        int pos = atomicAdd(&dcur[(p >> 16) & 255], 1);
        colbuf[pos] = (int)(p & 0xFFFFu);
    }
    __syncthreads();

    for (int i = tid; i < cb; i += 256) col[base + i] = colbuf[i];
}

// ==================== fused attention: both directions in one dispatch ====================
// grid (ceil(N/4), 2): blockIdx.y selects {QV,K,offs,col,out} set.
template<bool BF16_OUT>
__global__ __launch_bounds__(256) void attn_gather(const ushort* __restrict__ QV0,
                                                   const ushort* __restrict__ K0,
                                                   const int* __restrict__ offs0,
                                                   const int* __restrict__ col0,
                                                   void* __restrict__ out0,
                                                   const ushort* __restrict__ QV1,
                                                   const ushort* __restrict__ K1,
                                                   const int* __restrict__ offs1,
                                                   const int* __restrict__ col1,
                                                   void* __restrict__ out1, int n)
{
    const int y = blockIdx.y;
    const ushort* QV  = y ? QV1 : QV0;
    const ushort* K   = y ? K1  : K0;
    const int* offs   = y ? offs1 : offs0;
    const int* col    = y ? col1  : col0;
    void* outv        = y ? out1  : out0;

    const int wid  = (blockIdx.x * 256 + threadIdx.x) >> 6;
    const int lane = threadIdx.x & 63;
    if (wid >= n) return;
    const int li = lane & 15;
    const int g  = lane >> 4;

    const int beg = offs[wid], end = offs[wid + 1];

    uint4 ku = ((const uint4*)(K + (size_t)wid * DD))[li];
    float kf[8];
    {
        float2 t;
        t = bfp(ku.x); kf[0]=t.x; kf[1]=t.y;
        t = bfp(ku.y); kf[2]=t.x; kf[3]=t.y;
        t = bfp(ku.z); kf[4]=t.x; kf[5]=t.y;
        t = bfp(ku.w); kf[6]=t.x; kf[7]=t.y;
    }

    float m = -__builtin_inff();
    float den = 0.f;
    float acc[8] = {0.f,0.f,0.f,0.f,0.f,0.f,0.f,0.f};

    int p = beg + g;
    uint4 qn = make_uint4(0,0,0,0), vn = make_uint4(0,0,0,0);
    if (p < end) {
        const ushort* row = QV + (size_t)col[p] * 256;
        qn = ((const uint4*)row)[li];
        vn = ((const uint4*)(row + 128))[li];
    }

    while (p < end) {
        uint4 qu = qn, vu = vn;
        const int pn = p + 4;
        if (pn < end) {
            const ushort* row = QV + (size_t)col[pn] * 256;
            qn = ((const uint4*)row)[li];
            vn = ((const uint4*)(row + 128))[li];
        }
        float2 t;
        float d;
        t = bfp(qu.x); d  = t.x*kf[0] + t.y*kf[1];
        t = bfp(qu.y); d += t.x*kf[2] + t.y*kf[3];
        t = bfp(qu.z); d += t.x*kf[4] + t.y*kf[5];
        t = bfp(qu.w); d += t.x*kf[6] + t.y*kf[7];
        d += __shfl_xor(d, 1);
        d += __shfl_xor(d, 2);
        d += __shfl_xor(d, 4);
        d += __shfl_xor(d, 8);
        float sc = d * 0.08838834764831845f;      // 1/sqrt(128)
        sc = sc > 0.f ? sc : 0.01f * sc;          // leaky_relu
        float nm = fmaxf(m, sc);
        float f  = __expf(m - nm);                // first iter: exp(-inf)=0
        float pe = __expf(sc - nm);
        den = den * f + pe;
        float2 v0 = bfp(vu.x), v1 = bfp(vu.y), v2 = bfp(vu.z), v3 = bfp(vu.w);
        acc[0] = acc[0]*f + pe*v0.x;  acc[1] = acc[1]*f + pe*v0.y;
        acc[2] = acc[2]*f + pe*v1.x;  acc[3] = acc[3]*f + pe*v1.y;
        acc[4] = acc[4]*f + pe*v2.x;  acc[5] = acc[5]*f + pe*v2.y;
        acc[6] = acc[6]*f + pe*v3.x;  acc[7] = acc[7]*f + pe*v3.y;
        m = nm;
        p = pn;
    }

    // merge the 4 groups
    float m1 = fmaxf(m, __shfl_xor(m, 16));
    float m2 = fmaxf(m1, __shfl_xor(m1, 32));
    float f = (den > 0.f) ? __expf(m - m2) : 0.f;   // guard -inf - -inf
    den *= f;
    den += __shfl_xor(den, 16);
    den += __shfl_xor(den, 32);
    #pragma unroll
    for (int j = 0; j < 8; ++j) {
        acc[j] *= f;
        acc[j] += __shfl_xor(acc[j], 16);
        acc[j] += __shfl_xor(acc[j], 32);
    }
    if (g == 0) {
        const float inv = den > 0.f ? 1.f / den : 0.f;
        if (BF16_OUT) {
            ushort* o = (ushort*)outv + (size_t)wid * DD + li * 8;
            bf16x8 h;
            #pragma unroll
            for (int j = 0; j < 8; ++j) h[j] = (short)f2bf(acc[j] * inv);
            *(bf16x8*)o = h;
        } else {
            float* o = (float*)outv + (size_t)wid * DD + li * 8;
            *(float4*)o       = make_float4(acc[0]*inv, acc[1]*inv, acc[2]*inv, acc[3]*inv);
            *(float4*)(o + 4) = make_float4(acc[4]*inv, acc[5]*inv, acc[6]*inv, acc[7]*inv);
        }
    }
}

// ==================== host ====================
extern "C" void kernel_launch(void* const* d_in, const int* in_sizes, int n_in,
                              void* d_out, int out_size, void* d_ws, size_t ws_size,
                              hipStream_t stream)
{
    const float* x_a    = (const float*)d_in[0];
    const float* x_b    = (const float*)d_in[1];
    const int*   ei_ab  = (const int*)d_in[2];
    const int*   ei_ba  = (const int*)d_in[3];
    const float* qkv_w  = (const float*)d_in[4];
    const float* qkv_b  = (const float*)d_in[5];
    const float* edge_W = (const float*)d_in[6];
    float* out = (float*)d_out;

    const int N = in_sizes[0] / DD;    // 50000
    const int E = in_sizes[2] / 2;     // 600000
    const int nbkt = (N + 255) >> 8;   // 196

    float* ws = (float*)d_ws;
    float* WC  = ws;                         // 4*128*128 f32
    float* BCq = WC + 4 * DD * DD;           // 4*128 f32
    float* B3  = BCq + 4 * DD;               // 4*384 f32
    ushort* W3P = (ushort*)(B3 + 4 * 384);   // 4*49152 bf16
    ushort* HA  = W3P + (size_t)4 * 49152;   // layer-1 out a bf16 [N*128]
    ushort* HB  = HA + (size_t)N * DD;       // layer-1 out b bf16
    ushort* QVa = HB + (size_t)N * DD;       // q|v type a [N*256] bf16
    ushort* QVb = QVa + (size_t)N * 256;     // q|v type b
    ushort* FKa = QVb + (size_t)N * 256;     // k type a [N*128] bf16
    ushort* FKb = FKa + (size_t)N * DD;      // k type b
    int* ip      = (int*)(FKb + (size_t)N * DD);
    int* bcnt    = ip;                           // [512]
    int* bbase   = bcnt + 512;                   // [512]
    int* bcur    = bbase + 512;                  // [512]
    int* offs_ab = bcur + 512;                   // [N+1]
    int* offs_ba = offs_ab + (N + 1);            // [N+1]
    int* col_ab  = offs_ba + (N + 1);            // [E]
    int* col_ba  = col_ab + E;                   // [E]
    unsigned* stage0 = (unsigned*)(col_ba + E);  // [E]
    unsigned* stage1 = stage0 + E;               // [E]

    // ---- weight prep ----
    {
        dim3 g1(64, 4);
        combine_all<<<g1, 256, 0, stream>>>(qkv_w, qkv_b, edge_W, WC, BCq);
        dim3 g2(24, 4);
        pack_all<<<g2, 256, 0, stream>>>(qkv_w, qkv_b, WC, BCq, W3P, B3);
    }

    // ---- CSR via two-level bucket sort (reused by both layers) ----
    const int* s_ab = ei_ab;  const int* d_ab = ei_ab + E;
    const int* s_ba = ei_ba;  const int* d_ba = ei_ba + E;
    {
        zero_ints<<<2, 256, 0, stream>>>(bcnt, 512);
        dim3 hg(128, 2);
        bkt_hist<<<hg, 256, 0, stream>>>(d_ab, d_ba, bcnt, E);
        bkt_scan<<<1, 64, 0, stream>>>(bcnt, bbase, bcur, offs_ab, offs_ba, N, E);
        dim3 pg((E + CHUNK - 1) / CHUNK, 2);
        bkt_part<<<pg, 256, 0, stream>>>(s_ab, d_ab, s_ba, d_ba, bcur,
                                         stage0, stage1, E, nbkt);
        dim3 fg(nbkt, 2);
        bkt_fill<<<fg, 256, 0, stream>>>(stage0, stage1, bcnt, bbase,
                                         offs_ab, offs_ba, col_ab, col_ba, N);
    }

    const dim3 gemm_grid((N + 127) / 128, 2);
    const dim3 ag_grid((N + 3) / 4, 2);

    // ---- layer 1: fused GEMM (f32 inputs), merged attends (bf16 H out) ----
    gemm_mfma<true, false><<<gemm_grid, 256, 0, stream>>>(
        x_a, x_b, W3P, B3, QVa, FKa, QVb, FKb, N);
    attn_gather<true><<<ag_grid, 256, 0, stream>>>(
        QVa, FKb, offs_ab, col_ab, HB,
        QVb, FKa, offs_ba, col_ba, HA, N);

    // ---- layer 2: fused GEMM (bf16+relu inputs), merged attends (f32 out) ----
    float* o_a = out;
    float* o_b = out + (size_t)N * DD;
    gemm_mfma<false, true><<<gemm_grid, 256, 0, stream>>>(
        HA, HB, W3P + (size_t)2 * 49152, B3 + 2 * 384, QVa, FKa, QVb, FKb, N);
    attn_gather<false><<<ag_grid, 256, 0, stream>>>(
        QVa, FKb, offs_ab, col_ab, o_b,
        QVb, FKa, offs_ba, col_ba, o_a, N);
}

// Round 15
// 310.991 us; speedup vs baseline: 1.5932x; 1.5932x over previous
//
#include <hip/hip_runtime.h>
#include <math.h>

#define DD 128
#define CHUNK 8192
#define CAP 5120

typedef __attribute__((ext_vector_type(8))) short bf16x8;  // 8 bf16 (4 VGPR)
typedef __attribute__((ext_vector_type(4))) float f32x4;   // 4 fp32 acc
typedef __attribute__((ext_vector_type(4))) unsigned short u16x4;

__device__ __forceinline__ ushort f2bf(float f) {
    union { float f; unsigned u; } v; v.f = f;
    unsigned r = v.u + 0x7fff + ((v.u >> 16) & 1);   // RNE
    return (ushort)(r >> 16);
}

__device__ __forceinline__ float2 bfp(unsigned u) {
    union { unsigned x; float f; } a, b;
    a.x = u << 16;
    b.x = u & 0xffff0000u;
    return make_float2(a.f, b.f);
}

// ==================== weight prep (once per launch) ====================
__global__ __launch_bounds__(256) void combine_all(const float* __restrict__ qkv_w,
                                                   const float* __restrict__ qkv_b,
                                                   const float* __restrict__ edge_W,
                                                   float* __restrict__ WC,
                                                   float* __restrict__ BCq)
{
    const int z = blockIdx.y;          // (L<<1)|t
    const int L = z >> 1, t = z & 1;
    const float* wq = qkv_w + (((size_t)L * 2 + t) * 3 + 0) * DD * DD;
    const float* bq = qkv_b + (((size_t)L * 2 + t) * 3 + 0) * DD;
    const float* We = edge_W + ((size_t)L * 2 + t) * DD * DD;
    float* Wz = WC + (size_t)z * DD * DD;
    float* Bz = BCq + (size_t)z * DD;

    const int tid = threadIdx.x;
    const int i = blockIdx.x * 2 + (tid >> 7);
    const int j = tid & 127;
    float sum = 0.f;
    for (int k = 0; k < DD; ++k) sum = fmaf(wq[i * DD + k], We[k * DD + j], sum);
    Wz[i * DD + j] = sum;
    if (blockIdx.x == 0 && tid < DD) {
        float s2 = 0.f;
        for (int k = 0; k < DD; ++k) s2 = fmaf(bq[k], We[k * DD + j], s2);
        Bz[j] = s2;
    }
}

// Pack per z=(L,t): planes [q(Wc z) | v(wv L,t) | k(wk L,t)]
__global__ __launch_bounds__(256) void pack_all(const float* __restrict__ qkv_w,
                                                const float* __restrict__ qkv_b,
                                                const float* __restrict__ WC,
                                                const float* __restrict__ BCq,
                                                ushort* __restrict__ W3P,
                                                float* __restrict__ B3)
{
    const int z = blockIdx.y;
    const int L = z >> 1, t = z & 1;
    const int ci = blockIdx.x * 256 + threadIdx.x;     // 0..6143
    const int cb = ci >> 11;
    const int ct = (ci >> 8) & 7;
    const int ks = (ci >> 6) & 3;
    const int l  = ci & 63;
    const int c3 = cb * 128 + ct * 16 + (l & 15);
    const int k0 = ks * 32 + (l >> 4) * 8;

    const float* wv = qkv_w + (((size_t)L * 2 + t) * 3 + 2) * DD * DD;
    const float* wk = qkv_w + (((size_t)L * 2 + t) * 3 + 1) * DD * DD;
    const float* src;
    int cc;
    if (c3 < 128)      { src = WC + (size_t)z * DD * DD; cc = c3; }
    else if (c3 < 256) { src = wv; cc = c3 - 128; }
    else               { src = wk; cc = c3 - 256; }

    ushort h[8];
    #pragma unroll
    for (int j = 0; j < 8; ++j) h[j] = f2bf(src[(size_t)(k0 + j) * DD + cc]);
    ushort* dst = W3P + (size_t)z * 6144 * 8 + (size_t)ci * 8;
    #pragma unroll
    for (int j = 0; j < 8; ++j) dst[j] = h[j];

    if (ci < 384) {
        float bv;
        if (ci < 128)      bv = BCq[(size_t)z * DD + ci];
        else if (ci < 256) bv = qkv_b[(((size_t)L * 2 + t) * 3 + 2) * DD + (ci - 128)];
        else               bv = qkv_b[(((size_t)L * 2 + t) * 3 + 1) * DD + (ci - 256)];
        B3[(size_t)z * 384 + ci] = bv;
    }
}

// ==================== fused MFMA GEMM: swapped operands, X once, W-plane in LDS ====================
// grid (ceil(N/64), 2): block (x, t) computes q,v,k for 64 nodes of type t.  (R13 known-good)
template<bool F32_IN, bool RELU_IN>
__global__ __launch_bounds__(256, 4) void gemm_mfma(const void* __restrict__ Xav,
                                                    const void* __restrict__ Xbv,
                                                    const ushort* __restrict__ WpL,
                                                    const float* __restrict__ bL,
                                                    ushort* __restrict__ QVa,
                                                    ushort* __restrict__ FKa,
                                                    ushort* __restrict__ QVb,
                                                    ushort* __restrict__ FKb,
                                                    int N)
{
    const int t = blockIdx.y;
    ushort* QV = t ? QVb : QVa;
    ushort* FK = t ? FKb : FKa;
    const ushort* Wz = WpL + (size_t)t * 49152;
    const float* bz0 = bL + t * 384;

    __shared__ ushort Ws[16384];   // 32 KB, one plane at a time

    const int tid  = threadIdx.x;
    const int wave = tid >> 6;
    const int lane = tid & 63;
    const int node = blockIdx.x * 64 + wave * 16 + (lane & 15);
    const bool ok  = node < N;
    const int kc   = (lane >> 4) * 8;
    const int frow = (lane >> 4) * 4;

    // X fragments (B-operand): lane holds X[node][kc + ks*32 .. +8]; loaded ONCE.
    bf16x8 x[4];
    if (F32_IN) {
        const float* X = (const float*)(t ? Xbv : Xav);
        const float* xr = X + (size_t)node * DD + kc;
        #pragma unroll
        for (int ks = 0; ks < 4; ++ks) {
            bf16x8 h = (bf16x8){0,0,0,0,0,0,0,0};
            if (ok) {
                float4 v0 = *(const float4*)&xr[ks * 32];
                float4 v1 = *(const float4*)&xr[ks * 32 + 4];
                h[0]=(short)f2bf(v0.x); h[1]=(short)f2bf(v0.y); h[2]=(short)f2bf(v0.z); h[3]=(short)f2bf(v0.w);
                h[4]=(short)f2bf(v1.x); h[5]=(short)f2bf(v1.y); h[6]=(short)f2bf(v1.z); h[7]=(short)f2bf(v1.w);
            }
            x[ks] = h;
        }
    } else {
        const ushort* X = (const ushort*)(t ? Xbv : Xav);
        const ushort* xr = X + (size_t)node * DD + kc;
        #pragma unroll
        for (int ks = 0; ks < 4; ++ks) {
            bf16x8 h = (bf16x8){0,0,0,0,0,0,0,0};
            if (ok) h = *(const bf16x8*)&xr[ks * 32];
            if (RELU_IN) {
                #pragma unroll
                for (int j = 0; j < 8; ++j)
                    h[j] = (short)(((ushort)h[j] & 0x8000u) ? 0 : (ushort)h[j]);
            }
            x[ks] = h;
        }
    }

    #pragma unroll
    for (int p = 0; p < 3; ++p) {
        if (p) __syncthreads();   // all waves done reading Ws for plane p-1
        // stage W plane p: linear 16B copy, conflict-free
        #pragma unroll
        for (int i = 0; i < 8; ++i) {
            const int c = tid + i * 256;
            *(float4*)&Ws[(size_t)c * 8] = ((const float4*)(Wz + (size_t)p * 16384))[c];
        }
        __syncthreads();

        f32x4 acc[8];
        #pragma unroll
        for (int ct = 0; ct < 8; ++ct) {
            acc[ct] = (f32x4){0.f, 0.f, 0.f, 0.f};
            #pragma unroll
            for (int ks = 0; ks < 4; ++ks) {
                bf16x8 w = *(const bf16x8*)&Ws[(size_t)((ct * 4 + ks) * 64 + lane) * 8];
                acc[ct] = __builtin_amdgcn_mfma_f32_16x16x32_bf16(w, x[ks], acc[ct], 0, 0, 0);
            }
        }

        if (ok) {
            ushort* outp   = (p == 2) ? FK : QV;
            const int stride = (p == 2) ? 128 : 256;
            const int off    = (p == 1) ? 128 : 0;
            const float* bzp = bz0 + p * 128;
            ushort* orow = outp + (size_t)node * stride + off;
            #pragma unroll
            for (int ct = 0; ct < 8; ++ct) {
                const float4 bv = *(const float4*)&bzp[ct * 16 + frow];
                u16x4 o;
                o[0] = f2bf(acc[ct][0] + bv.x);
                o[1] = f2bf(acc[ct][1] + bv.y);
                o[2] = f2bf(acc[ct][2] + bv.z);
                o[3] = f2bf(acc[ct][3] + bv.w);
                *(u16x4*)&orow[ct * 16 + frow] = o;   // single 8B store
            }
        }
    }
}

// ==================== CSR build: two-level bucket counting sort ====================
__global__ __launch_bounds__(256) void zero_ints(int* __restrict__ p, int n)
{
    int i = blockIdx.x * 256 + threadIdx.x;
    if (i < n) p[i] = 0;
}

__global__ __launch_bounds__(256) void bkt_hist(const int* __restrict__ dst0,
                                                const int* __restrict__ dst1,
                                                int* __restrict__ bcnt, int nE)
{
    const int t = blockIdx.y;
    const int* dst = t ? dst1 : dst0;
    __shared__ int h[256];
    h[threadIdx.x] = 0;
    __syncthreads();
    for (int e = blockIdx.x * 256 + threadIdx.x; e < nE; e += gridDim.x * 256)
        atomicAdd(&h[dst[e] >> 8], 1);
    __syncthreads();
    if (h[threadIdx.x]) atomicAdd(&bcnt[t * 256 + threadIdx.x], h[threadIdx.x]);
}

__global__ __launch_bounds__(64) void bkt_scan(const int* __restrict__ bcnt,
                                               int* __restrict__ bbase,
                                               int* __restrict__ bcur,
                                               int* __restrict__ offs0,
                                               int* __restrict__ offs1, int N, int nE)
{
    if (threadIdx.x < 2) {
        int t = threadIdx.x;
        int run = 0;
        for (int i = 0; i < 256; ++i) {
            int v = bcnt[t * 256 + i];
            bbase[t * 256 + i] = run;
            bcur[t * 256 + i] = run;
            run += v;
        }
        if (t == 0) offs0[N] = nE; else offs1[N] = nE;
    }
}

__global__ __launch_bounds__(256) void bkt_part(const int* __restrict__ src0,
                                                const int* __restrict__ dst0,
                                                const int* __restrict__ src1,
                                                const int* __restrict__ dst1,
                                                int* __restrict__ bcur,
                                                unsigned* __restrict__ stage0,
                                                unsigned* __restrict__ stage1,
                                                int nE, int nbkt)
{
    const int t = blockIdx.y;
    const int* src = t ? src1 : src0;
    const int* dst = t ? dst1 : dst0;
    unsigned* stage = t ? stage1 : stage0;
    int* bc = bcur + t * 256;

    __shared__ unsigned ebuf[CHUNK];                   // 32 KB
    __shared__ int cnt[256], loff[256], cur[256], resv[256];

    const int tid  = threadIdx.x;
    const int e0   = blockIdx.x * CHUNK;
    const int ecnt = min(CHUNK, nE - e0);

    cnt[tid] = 0;
    __syncthreads();

    unsigned pk[CHUNK / 256];
    #pragma unroll
    for (int i = 0; i < CHUNK / 256; ++i) {
        const int le = i * 256 + tid;
        unsigned p = 0xFFFFFFFFu;
        if (le < ecnt) {
            int d = dst[e0 + le], s = src[e0 + le];
            p = ((unsigned)(d >> 8) << 24) | ((unsigned)(d & 255) << 16) | (unsigned)s;
            atomicAdd(&cnt[d >> 8], 1);
        }
        pk[i] = p;
    }
    __syncthreads();

    int v = cnt[tid];
    loff[tid] = v;
    __syncthreads();
    for (int off = 1; off < 256; off <<= 1) {
        int a = (tid >= off) ? loff[tid - off] : 0;
        __syncthreads();
        loff[tid] += a;
        __syncthreads();
    }
    int excl = loff[tid] - v;
    __syncthreads();
    loff[tid] = excl;
    cur[tid]  = excl;
    __syncthreads();

    #pragma unroll
    for (int i = 0; i < CHUNK / 256; ++i) {
        unsigned p = pk[i];
        if (p != 0xFFFFFFFFu) {
            int b = p >> 24;
            int pos = atomicAdd(&cur[b], 1);
            ebuf[pos] = p;
        }
    }
    __syncthreads();

    if (tid < nbkt && cnt[tid] > 0) resv[tid] = atomicAdd(&bc[tid], cnt[tid]);
    __syncthreads();

    const int wv = tid >> 6, ln = tid & 63;
    for (int b = wv; b < nbkt; b += 4) {
        const int c = cnt[b];
        if (c == 0) continue;
        const int lo = loff[b];
        const int rb = resv[b];
        for (int i = ln; i < c; i += 64) stage[rb + i] = ebuf[lo + i];
    }
}

__global__ __launch_bounds__(256) void bkt_fill(const unsigned* __restrict__ stage0,
                                                const unsigned* __restrict__ stage1,
                                                const int* __restrict__ bcnt,
                                                const int* __restrict__ bbase,
                                                int* __restrict__ offs0,
                                                int* __restrict__ offs1,
                                                int* __restrict__ col0,
                                                int* __restrict__ col1, int N)
{
    const int b = blockIdx.x, t = blockIdx.y;
    const unsigned* stage = t ? stage1 : stage0;
    int* offs = t ? offs1 : offs0;
    int* col  = t ? col1 : col0;
    const int base = bbase[t * 256 + b];
    int cb = bcnt[t * 256 + b];
    if (cb > CAP) cb = CAP;

    __shared__ unsigned ebuf[CAP];
    __shared__ int colbuf[CAP];
    __shared__ int dcnt[256], doff[256], dcur[256];

    const int tid = threadIdx.x;
    dcnt[tid] = 0;
    __syncthreads();

    for (int i = tid; i < cb; i += 256) {
        unsigned p = stage[base + i];
        ebuf[i] = p;
        atomicAdd(&dcnt[(p >> 16) & 255], 1);
    }
    __syncthreads();

    int v = dcnt[tid];
    doff[tid] = v;
    __syncthreads();
    for (int off = 1; off < 256; off <<= 1) {
        int a = (tid >= off) ? doff[tid - off] : 0;
        __syncthreads();
        doff[tid] += a;
        __syncthreads();
    }
    int excl = doff[tid] - v;
    dcur[tid] = excl;
    const int node = (b << 8) + tid;
    if (node < N) offs[node] = base + excl;
    __syncthreads();

    for (int i = tid; i < cb; i += 256) {
        unsigned p = ebuf[i];
        int pos = atomicAdd(&dcur[(p >> 16) & 255], 1);
        colbuf[pos] = (int)(p & 0xFFFFu);
    }
    __syncthreads();

    for (int i = tid; i < cb; i += 256) col[base + i] = colbuf[i];
}

// ==================== fused attention: both directions in one dispatch ====================
// grid (ceil(N/4), 2): blockIdx.y selects {QV,K,offs,col,out} set.
template<bool BF16_OUT>
__global__ __launch_bounds__(256) void attn_gather(const ushort* __restrict__ QV0,
                                                   const ushort* __restrict__ K0,
                                                   const int* __restrict__ offs0,
                                                   const int* __restrict__ col0,
                                                   void* __restrict__ out0,
                                                   const ushort* __restrict__ QV1,
                                                   const ushort* __restrict__ K1,
                                                   const int* __restrict__ offs1,
                                                   const int* __restrict__ col1,
                                                   void* __restrict__ out1, int n)
{
    const int y = blockIdx.y;
    const ushort* QV  = y ? QV1 : QV0;
    const ushort* K   = y ? K1  : K0;
    const int* offs   = y ? offs1 : offs0;
    const int* col    = y ? col1  : col0;
    void* outv        = y ? out1  : out0;

    const int wid  = (blockIdx.x * 256 + threadIdx.x) >> 6;
    const int lane = threadIdx.x & 63;
    if (wid >= n) return;
    const int li = lane & 15;
    const int g  = lane >> 4;

    const int beg = offs[wid], end = offs[wid + 1];

    uint4 ku = ((const uint4*)(K + (size_t)wid * DD))[li];
    float kf[8];
    {
        float2 t;
        t = bfp(ku.x); kf[0]=t.x; kf[1]=t.y;
        t = bfp(ku.y); kf[2]=t.x; kf[3]=t.y;
        t = bfp(ku.z); kf[4]=t.x; kf[5]=t.y;
        t = bfp(ku.w); kf[6]=t.x; kf[7]=t.y;
    }

    float m = -__builtin_inff();
    float den = 0.f;
    float acc[8] = {0.f,0.f,0.f,0.f,0.f,0.f,0.f,0.f};

    int p = beg + g;
    uint4 qn = make_uint4(0,0,0,0), vn = make_uint4(0,0,0,0);
    if (p < end) {
        const ushort* row = QV + (size_t)col[p] * 256;
        qn = ((const uint4*)row)[li];
        vn = ((const uint4*)(row + 128))[li];
    }

    while (p < end) {
        uint4 qu = qn, vu = vn;
        const int pn = p + 4;
        if (pn < end) {
            const ushort* row = QV + (size_t)col[pn] * 256;
            qn = ((const uint4*)row)[li];
            vn = ((const uint4*)(row + 128))[li];
        }
        float2 t;
        float d;
        t = bfp(qu.x); d  = t.x*kf[0] + t.y*kf[1];
        t = bfp(qu.y); d += t.x*kf[2] + t.y*kf[3];
        t = bfp(qu.z); d += t.x*kf[4] + t.y*kf[5];
        t = bfp(qu.w); d += t.x*kf[6] + t.y*kf[7];
        d += __shfl_xor(d, 1);
        d += __shfl_xor(d, 2);
        d += __shfl_xor(d, 4);
        d += __shfl_xor(d, 8);
        float sc = d * 0.08838834764831845f;      // 1/sqrt(128)
        sc = sc > 0.f ? sc : 0.01f * sc;          // leaky_relu
        float nm = fmaxf(m, sc);
        float f  = __expf(m - nm);                // first iter: exp(-inf)=0
        float pe = __expf(sc - nm);
        den = den * f + pe;
        float2 v0 = bfp(vu.x), v1 = bfp(vu.y), v2 = bfp(vu.z), v3 = bfp(vu.w);
        acc[0] = acc[0]*f + pe*v0.x;  acc[1] = acc[1]*f + pe*v0.y;
        acc[2] = acc[2]*f + pe*v1.x;  acc[3] = acc[3]*f + pe*v1.y;
        acc[4] = acc[4]*f + pe*v2.x;  acc[5] = acc[5]*f + pe*v2.y;
        acc[6] = acc[6]*f + pe*v3.x;  acc[7] = acc[7]*f + pe*v3.y;
        m = nm;
        p = pn;
    }

    // merge the 4 groups
    float m1 = fmaxf(m, __shfl_xor(m, 16));
    float m2 = fmaxf(m1, __shfl_xor(m1, 32));
    float f = (den > 0.f) ? __expf(m - m2) : 0.f;   // guard -inf - -inf
    den *= f;
    den += __shfl_xor(den, 16);
    den += __shfl_xor(den, 32);
    #pragma unroll
    for (int j = 0; j < 8; ++j) {
        acc[j] *= f;
        acc[j] += __shfl_xor(acc[j], 16);
        acc[j] += __shfl_xor(acc[j], 32);
    }
    if (g == 0) {
        const float inv = den > 0.f ? 1.f / den : 0.f;
        if (BF16_OUT) {
            ushort* o = (ushort*)outv + (size_t)wid * DD + li * 8;
            bf16x8 h;
            #pragma unroll
            for (int j = 0; j < 8; ++j) h[j] = (short)f2bf(acc[j] * inv);
            *(bf16x8*)o = h;
        } else {
            float* o = (float*)outv + (size_t)wid * DD + li * 8;
            *(float4*)o       = make_float4(acc[0]*inv, acc[1]*inv, acc[2]*inv, acc[3]*inv);
            *(float4*)(o + 4) = make_float4(acc[4]*inv, acc[5]*inv, acc[6]*inv, acc[7]*inv);
        }
    }
}

// ==================== host ====================
extern "C" void kernel_launch(void* const* d_in, const int* in_sizes, int n_in,
                              void* d_out, int out_size, void* d_ws, size_t ws_size,
                              hipStream_t stream)
{
    const float* x_a    = (const float*)d_in[0];
    const float* x_b    = (const float*)d_in[1];
    const int*   ei_ab  = (const int*)d_in[2];
    const int*   ei_ba  = (const int*)d_in[3];
    const float* qkv_w  = (const float*)d_in[4];
    const float* qkv_b  = (const float*)d_in[5];
    const float* edge_W = (const float*)d_in[6];
    float* out = (float*)d_out;

    const int N = in_sizes[0] / DD;    // 50000
    const int E = in_sizes[2] / 2;     // 600000
    const int nbkt = (N + 255) >> 8;   // 196

    float* ws = (float*)d_ws;
    float* WC  = ws;                         // 4*128*128 f32
    float* BCq = WC + 4 * DD * DD;           // 4*128 f32
    float* B3  = BCq + 4 * DD;               // 4*384 f32
    ushort* W3P = (ushort*)(B3 + 4 * 384);   // 4*49152 bf16
    ushort* HA  = W3P + (size_t)4 * 49152;   // layer-1 out a bf16 [N*128]
    ushort* HB  = HA + (size_t)N * DD;       // layer-1 out b bf16
    ushort* QVa = HB + (size_t)N * DD;       // q|v type a [N*256] bf16
    ushort* QVb = QVa + (size_t)N * 256;     // q|v type b
    ushort* FKa = QVb + (size_t)N * 256;     // k type a [N*128] bf16
    ushort* FKb = FKa + (size_t)N * DD;      // k type b
    int* ip      = (int*)(FKb + (size_t)N * DD);
    int* bcnt    = ip;                           // [512]
    int* bbase   = bcnt + 512;                   // [512]
    int* bcur    = bbase + 512;                  // [512]
    int* offs_ab = bcur + 512;                   // [N+1]
    int* offs_ba = offs_ab + (N + 1);            // [N+1]
    int* col_ab  = offs_ba + (N + 1);            // [E]
    int* col_ba  = col_ab + E;                   // [E]
    unsigned* stage0 = (unsigned*)(col_ba + E);  // [E]
    unsigned* stage1 = stage0 + E;               // [E]

    // ---- weight prep ----
    {
        dim3 g1(64, 4);
        combine_all<<<g1, 256, 0, stream>>>(qkv_w, qkv_b, edge_W, WC, BCq);
        dim3 g2(24, 4);
        pack_all<<<g2, 256, 0, stream>>>(qkv_w, qkv_b, WC, BCq, W3P, B3);
    }

    // ---- CSR via two-level bucket sort (reused by both layers) ----
    const int* s_ab = ei_ab;  const int* d_ab = ei_ab + E;
    const int* s_ba = ei_ba;  const int* d_ba = ei_ba + E;
    {
        zero_ints<<<2, 256, 0, stream>>>(bcnt, 512);
        dim3 hg(128, 2);
        bkt_hist<<<hg, 256, 0, stream>>>(d_ab, d_ba, bcnt, E);
        bkt_scan<<<1, 64, 0, stream>>>(bcnt, bbase, bcur, offs_ab, offs_ba, N, E);
        dim3 pg((E + CHUNK - 1) / CHUNK, 2);
        bkt_part<<<pg, 256, 0, stream>>>(s_ab, d_ab, s_ba, d_ba, bcur,
                                         stage0, stage1, E, nbkt);
        dim3 fg(nbkt, 2);
        bkt_fill<<<fg, 256, 0, stream>>>(stage0, stage1, bcnt, bbase,
                                         offs_ab, offs_ba, col_ab, col_ba, N);
    }

    const dim3 gemm_grid((N + 63) / 64, 2);
    const dim3 ag_grid((N + 3) / 4, 2);

    // ---- layer 1: fused GEMM (f32 inputs), merged attends (bf16 H out) ----
    gemm_mfma<true, false><<<gemm_grid, 256, 0, stream>>>(
        x_a, x_b, W3P, B3, QVa, FKa, QVb, FKb, N);
    attn_gather<true><<<ag_grid, 256, 0, stream>>>(
        QVa, FKb, offs_ab, col_ab, HB,
        QVb, FKa, offs_ba, col_ba, HA, N);

    // ---- layer 2: fused GEMM (bf16+relu inputs), merged attends (f32 out) ----
    float* o_a = out;
    float* o_b = out + (size_t)N * DD;
    gemm_mfma<false, true><<<gemm_grid, 256, 0, stream>>>(
        HA, HB, W3P + (size_t)2 * 49152, B3 + 2 * 384, QVa, FKa, QVb, FKb, N);
    attn_gather<false><<<ag_grid, 256, 0, stream>>>(
        QVa, FKb, offs_ab, col_ab, o_b,
        QVb, FKa, offs_ba, col_ba, o_a, N);
}